// Round 13
// baseline (229.477 us; speedup 1.0000x reference)
//
#include <hip/hip_runtime.h>
#include <math.h>

#define N_ATOMS 4096
#define L_WORDS 65536
#define DD 10
#define HALO 11

#define CONV_BLOCKS 256
#define CONV_BLOCK 256
#define RPB 4                     // rows per block (contiguous 64 KB slab)
#define GNN_BLOCKS 1024           // 4096/4 row-slabs
#define TOTAL_BLOCKS 1280         // 256 conv + 1024 gnn
#define ATT_BLOCKS 256
#define SH_FLOATS 2926            // max(conv halo 266*11 = 2926, stash 160)

// ---------------------------------------------------------------------------
// K0: embedding gather -> xs0 planes + hs0 = relu(W0 xs0 + b0) planes.
// ---------------------------------------------------------------------------
__global__ __launch_bounds__(128) void gnn_embed(
    const int* __restrict__ fp, const float* __restrict__ embed_fp,
    const float* __restrict__ Wg, const float* __restrict__ bg,
    float* __restrict__ xs, float* __restrict__ hs)
{
    const int n = blockIdx.x * 128 + threadIdx.x;   // grid 32x128 = 4096
    float x[DD];
    const float* e = embed_fp + (size_t)fp[n] * DD;
    #pragma unroll
    for (int d = 0; d < DD; ++d) x[d] = e[d];
    #pragma unroll
    for (int d = 0; d < DD; ++d) xs[d * N_ATOMS + n] = x[d];
    #pragma unroll
    for (int d = 0; d < DD; ++d) {
        float v = bg[d];
        #pragma unroll
        for (int k = 0; k < DD; ++k) v += Wg[d * DD + k] * x[k];
        hs[d * N_ATOMS + n] = fmaxf(v, 0.f);
    }
}

// ---------------------------------------------------------------------------
// K_prep: xs_{i+1} = xs_i + part_i ; hs_{i+1} = relu(W xs + b).
// (part is now the FULL A@hs rows — no quarter sum.)
// ---------------------------------------------------------------------------
__global__ __launch_bounds__(128) void gnn_prep(
    const float* __restrict__ xs_in, const float* __restrict__ part,
    const float* __restrict__ Wg, const float* __restrict__ bg,
    float* __restrict__ xs_out, float* __restrict__ hs)
{
    const int n = blockIdx.x * 128 + threadIdx.x;   // grid 32x128
    float x[DD];
    #pragma unroll
    for (int d = 0; d < DD; ++d) {
        float v = xs_in[d * N_ATOMS + n] + part[d * N_ATOMS + n];
        x[d] = v;
        xs_out[d * N_ATOMS + n] = v;
    }
    #pragma unroll
    for (int d = 0; d < DD; ++d) {
        float v = bg[d];
        #pragma unroll
        for (int k = 0; k < DD; ++k) v += Wg[d * DD + k] * x[k];
        hs[d * N_ATOMS + n] = fmaxf(v, 0.f);
    }
}

// ---------------------------------------------------------------------------
// conv stage: one CNN layer over this block's 256 words.
// If hpb != null, also fuses hp = relu(Wa·relu(acc)+ba) for its own words.
// ---------------------------------------------------------------------------
__device__ __forceinline__ void conv_stage(
    float* sh, const int tid, const int bx,
    const float* __restrict__ tin, const int* __restrict__ words,
    const float* __restrict__ embed_word, const float* __restrict__ w,
    const float* __restrict__ bptr, float* __restrict__ tout,
    const float* __restrict__ Wa, const float* __restrict__ ba,
    float* __restrict__ hpb)
{
    const int l0 = bx * CONV_BLOCK;
    for (int idx = tid; idx < (CONV_BLOCK + 2 * HALO) * DD; idx += CONV_BLOCK) {
        int rr = idx / DD, d = idx - rr * DD;
        int gr = l0 - HALO + rr;
        float v = 0.f;
        if (gr >= 0 && gr < L_WORDS) {
            if (tin) v = tin[(size_t)gr * DD + d];
            else     v = embed_word[(size_t)words[gr] * DD + d];
        }
        sh[rr * 11 + d] = v;
    }
    __syncthreads();

    const float bias = *bptr;
    float acc[DD];
    #pragma unroll
    for (int d = 0; d < DD; ++d) acc[d] = bias;
    for (int i = 0; i < 23; ++i) {
        float row[DD];
        const float* sr = &sh[(tid + i) * 11];
        #pragma unroll
        for (int c = 0; c < DD; ++c) row[c] = sr[c];
        #pragma unroll
        for (int d = 0; d < DD; ++d) {
            #pragma unroll
            for (int c = 0; c < DD; ++c)
                acc[d] += row[c] * w[i * 23 + (c - d + 11)];
        }
    }
    const int l = l0 + tid;
    if (tout) {
        #pragma unroll
        for (int d = 0; d < DD; ++d)
            tout[(size_t)l * DD + d] = fmaxf(acc[d], 0.f);
    }
    if (hpb) {
        float xsp[DD];
        #pragma unroll
        for (int d = 0; d < DD; ++d) xsp[d] = fmaxf(acc[d], 0.f);
        #pragma unroll
        for (int d = 0; d < DD; ++d) {
            float v = ba[d];
            #pragma unroll
            for (int k = 0; k < DD; ++k) v += Wa[d * DD + k] * xsp[k];
            hpb[(size_t)l * DD + d] = fmaxf(v, 0.f);
        }
    }
}

// ---------------------------------------------------------------------------
// gnn stage: block b owns 4 CONTIGUOUS rows of A (one 64 KB span); its 4
// waves take column quarters. Per-wave instruction stream identical to R12
// (16 A-loads, 40 h-loads, 640 FMA) — only the block's A-footprint changes:
// 256 KB strided -> 64 KB contiguous (DRAM row-locality test). Block output
// is the FULL A@hs row (cross-quarter sum in LDS) — no part quarters.
// ---------------------------------------------------------------------------
__device__ __forceinline__ void gnn_stage(
    float* sh, const int tid, const int b,
    const float* __restrict__ hs,        // SoA [10][4096]
    const float* __restrict__ A, float* __restrict__ part_out)
{
    const int wave = tid >> 6, lane = tid & 63;
    const int r0 = b * RPB;              // 4 contiguous rows

    // wave's column quarter: cols [wave*1024, wave*1024+1024)
    const float4* A4 = (const float4*)A + (size_t)r0 * (N_ATOMS / 4) + wave * 256;
    const float4* h4 = (const float4*)hs + wave * 256;

    float acc[RPB][DD];
    #pragma unroll
    for (int r = 0; r < RPB; ++r)
        #pragma unroll
        for (int d = 0; d < DD; ++d) acc[r][d] = 0.f;

    #pragma unroll
    for (int it = 0; it < 4; ++it) {
        const int cb = it * 64 + lane;
        float4 a[RPB];
        #pragma unroll
        for (int r = 0; r < RPB; ++r) a[r] = A4[r * (N_ATOMS / 4) + cb];
        #pragma unroll
        for (int d = 0; d < DD; ++d) {
            float4 h = h4[d * (N_ATOMS / 4) + cb];
            #pragma unroll
            for (int r = 0; r < RPB; ++r) {
                acc[r][d] += a[r].x * h.x;
                acc[r][d] += a[r].y * h.y;
                acc[r][d] += a[r].z * h.z;
                acc[r][d] += a[r].w * h.w;
            }
        }
    }

    // ---- full-wave butterfly: every lane gets the wave's 1024-col sum ----
    #pragma unroll
    for (int m = 1; m <= 32; m <<= 1) {
        #pragma unroll
        for (int r = 0; r < RPB; ++r)
            #pragma unroll
            for (int d = 0; d < DD; ++d)
                acc[r][d] += __shfl_xor(acc[r][d], m, 64);
    }

    // lane 0 of each wave stashes its 40 quarter-sums
    if (lane == 0) {
        float* dst = &sh[wave * 40];
        #pragma unroll
        for (int r = 0; r < RPB; ++r)
            #pragma unroll
            for (int d = 0; d < DD; ++d) dst[r * DD + d] = acc[r][d];
    }
    __syncthreads();

    // threads 0..39: sum the 4 waves -> final rows, SoA write
    if (tid < RPB * DD) {
        const int r = tid & 3, d = tid >> 2;
        const int o = r * DD + d;
        float v = sh[o] + sh[40 + o] + sh[80 + o] + sh[120 + o];
        part_out[d * N_ATOMS + r0 + r] = v;
    }
}

// ---------------------------------------------------------------------------
// F: one pipeline step. blocks [0,256): conv layer; [256,1280): gnn layer.
// ---------------------------------------------------------------------------
__global__ __launch_bounds__(256, 4) void fused_layer(
    const float* __restrict__ A, const float* __restrict__ hs,
    float* __restrict__ part_out,
    const float* __restrict__ tin, const int* __restrict__ words,
    const float* __restrict__ emb_w, const float* __restrict__ wc,
    const float* __restrict__ bc, float* __restrict__ tout,
    const float* __restrict__ Wa, const float* __restrict__ ba,
    float* __restrict__ hpb)
{
    __shared__ float sh[SH_FLOATS];      // 11.7 KB
    const int tid = threadIdx.x;
    if (blockIdx.x < CONV_BLOCKS)
        conv_stage(sh, tid, blockIdx.x, tin, words, emb_w, wc, bc, tout,
                   Wa, ba, hpb);
    else
        gnn_stage(sh, tid, blockIdx.x - CONV_BLOCKS, hs, A, part_out);
}

// ---------------------------------------------------------------------------
// K_comp: comp partials computed ONCE (16 blocks x 256 atoms) -> comp_part.
// ---------------------------------------------------------------------------
__global__ __launch_bounds__(256) void comp_reduce(
    const float* __restrict__ xs, const float* __restrict__ p2,
    float* __restrict__ comp_part)
{
    const int tid = threadIdx.x, wave = tid >> 6, lane = tid & 63;
    const int n = blockIdx.x * 256 + tid;
    float x[DD];
    #pragma unroll
    for (int d = 0; d < DD; ++d)
        x[d] = xs[d * N_ATOMS + n] + p2[d * N_ATOMS + n];
    #pragma unroll
    for (int m = 32; m >= 1; m >>= 1) {
        #pragma unroll
        for (int d = 0; d < DD; ++d) x[d] += __shfl_xor(x[d], m, 64);
    }
    __shared__ float s[4][DD];
    if (lane == 0) {
        #pragma unroll
        for (int d = 0; d < DD; ++d) s[wave][d] = x[d];
    }
    __syncthreads();
    if (tid < DD)
        comp_part[blockIdx.x * DD + tid] =
            s[0][tid] + s[1][tid] + s[2][tid] + s[3][tid];
}

// ---------------------------------------------------------------------------
// ATTN+FINAL: 256 blocks x 256 threads (1 word/thread). Relaxed agent-scope
// atomic publication + last-block ticket election (proven rounds 4-12).
// ---------------------------------------------------------------------------
__global__ __launch_bounds__(256) void attn_final(
    const float* __restrict__ comp_part, const float* __restrict__ hpb,
    const float* __restrict__ Wa, const float* __restrict__ ba,
    const float* __restrict__ Wo, const float* __restrict__ bo,
    const float* __restrict__ Wi, const float* __restrict__ bi,
    float* att_part, unsigned int* ticket, float* __restrict__ out)
{
    __shared__ float red[4][DD];
    __shared__ float shc[DD];
    __shared__ float cat[20];
    __shared__ int islast;
    const int tid = threadIdx.x, wave = tid >> 6, lane = tid & 63;

    if (tid < DD) {
        float c = 0.f;
        #pragma unroll
        for (int p = 0; p < 16; ++p) c += comp_part[p * DD + tid];
        shc[tid] = c * (1.f / N_ATOMS);
    }
    __syncthreads();

    float h[DD];
    #pragma unroll
    for (int d = 0; d < DD; ++d) {
        float v = ba[d];
        #pragma unroll
        for (int k = 0; k < DD; ++k) v += Wa[d * DD + k] * shc[k];
        h[d] = fmaxf(v, 0.f);
    }
    const int w_ = blockIdx.x * 256 + tid;
    float hp[DD], dotv = 0.f;
    #pragma unroll
    for (int d = 0; d < DD; ++d) {
        hp[d] = hpb[(size_t)w_ * DD + d];
        dotv += h[d] * hp[d];
    }
    const float wgt = tanhf(dotv);
    float y[DD];
    #pragma unroll
    for (int d = 0; d < DD; ++d) y[d] = wgt * hp[d];
    #pragma unroll
    for (int m = 32; m >= 1; m >>= 1) {
        #pragma unroll
        for (int d = 0; d < DD; ++d) y[d] += __shfl_xor(y[d], m, 64);
    }
    if (lane == 0) {
        #pragma unroll
        for (int d = 0; d < DD; ++d) red[wave][d] = y[d];
    }
    __syncthreads();
    if (tid < DD) {
        float v = red[0][tid] + red[1][tid] + red[2][tid] + red[3][tid];
        __hip_atomic_store(att_part + blockIdx.x * DD + tid, v,
                           __ATOMIC_RELAXED, __HIP_MEMORY_SCOPE_AGENT);
    }
    __syncthreads();   // drains each wave's vmcnt -> stores globally visible

    if (tid == 0) {
        unsigned prev = __hip_atomic_fetch_add(ticket, 1u, __ATOMIC_RELAXED,
                                               __HIP_MEMORY_SCOPE_AGENT);
        islast = (prev == ATT_BLOCKS - 1);
    }
    __syncthreads();
    if (!islast) return;
    asm volatile("" ::: "memory");

    // ---- final: reduce 256 partials (1 per thread) + MLP ----
    float a[DD];
    #pragma unroll
    for (int d = 0; d < DD; ++d)
        a[d] = __hip_atomic_load(att_part + tid * DD + d,
                                 __ATOMIC_RELAXED, __HIP_MEMORY_SCOPE_AGENT);
    #pragma unroll
    for (int m = 32; m >= 1; m >>= 1) {
        #pragma unroll
        for (int d = 0; d < DD; ++d) a[d] += __shfl_xor(a[d], m, 64);
    }
    __syncthreads();                 // red[] reuse
    if (lane == 0) {
        #pragma unroll
        for (int d = 0; d < DD; ++d) red[wave][d] = a[d];
    }
    __syncthreads();
    if (tid < DD) {
        float pv = red[0][tid] + red[1][tid] + red[2][tid] + red[3][tid];
        cat[DD + tid] = pv * (1.f / L_WORDS);
        cat[tid] = shc[tid];
    }
    __syncthreads();
    for (int j = 0; j < 3; ++j) {
        float v = 0.f;
        if (tid < 20) {
            v = bo[j * 20 + tid];
            for (int k = 0; k < 20; ++k) v += Wo[j * 400 + tid * 20 + k] * cat[k];
        }
        __syncthreads();
        if (tid < 20) cat[tid] = fmaxf(v, 0.f);
        __syncthreads();
    }
    if (tid < 2) {
        float v = bi[tid];
        for (int k = 0; k < 20; ++k) v += Wi[tid * 20 + k] * cat[k];
        out[tid] = v;
    }
}

// ---------------------------------------------------------------------------
extern "C" void kernel_launch(void* const* d_in, const int* in_sizes, int n_in,
                              void* d_out, int out_size, void* d_ws, size_t ws_size,
                              hipStream_t stream)
{
    const int*   fp     = (const int*)d_in[0];
    const float* A      = (const float*)d_in[1];
    const int*   words  = (const int*)d_in[2];
    const float* emb_fp = (const float*)d_in[3];
    const float* emb_w  = (const float*)d_in[4];
    const float* Wg     = (const float*)d_in[5];   // [3][10][10]
    const float* bg     = (const float*)d_in[6];   // [3][10]
    const float* Wc     = (const float*)d_in[7];   // [3][529]
    const float* bc     = (const float*)d_in[8];   // [3]
    const float* Wa     = (const float*)d_in[9];   // [10][10]
    const float* ba     = (const float*)d_in[10];  // [10]
    const float* Wo     = (const float*)d_in[11];  // [3][20][20]
    const float* bo     = (const float*)d_in[12];  // [3][20]
    const float* Wi     = (const float*)d_in[13];  // [2][20]
    const float* bi     = (const float*)d_in[14];  // [2]
    float* out = (float*)d_out;
    float* ws  = (float*)d_ws;

    float* xs0   = ws;                       // 40960   SoA [10][4096]
    float* xs1   = ws + 40960;               // 40960
    float* xs2   = ws + 81920;               // 40960
    float* hs0   = ws + 122880;              // 40960   SoA planes
    float* hs1   = ws + 163840;              // 40960
    float* hs2   = ws + 204800;              // 40960
    float* part0 = ws + 245760;              // 40960   SoA [10][4096] (full rows)
    float* part1 = ws + 286720;              // 40960
    float* part2 = ws + 327680;              // 40960
    float* ta    = ws + 368640;              // 655360
    float* tb    = ws + 1024000;             // 655360
    float* hpb   = ta;                       // alias: ta dead after F1 reads it
    float* att_part  = ws + 1679360;         // 2560 (256 x 10)
    float* comp_part = ws + 1681920;         // 160
    unsigned int* ticket = (unsigned int*)(ws + 1682080);

    hipMemsetAsync(ticket, 0, sizeof(unsigned int), stream);

    // K0: embed gather once (tiny) -> xs0 + hs0 planes
    gnn_embed<<<N_ATOMS / 128, 128, 0, stream>>>(fp, emb_fp, Wg, bg, xs0, hs0);

    // F0: conv-L0 || gnn-L0
    fused_layer<<<TOTAL_BLOCKS, 256, 0, stream>>>(
        A, hs0, part0,
        nullptr, words, emb_w, Wc, bc, ta, nullptr, nullptr, nullptr);

    // P1: xs1 = xs0 + part0 ; hs1 = relu(W1 xs1 + b1)
    gnn_prep<<<N_ATOMS / 128, 128, 0, stream>>>(
        xs0, part0, Wg + 100, bg + 10, xs1, hs1);

    // F1: conv-L1 || gnn-L1
    fused_layer<<<TOTAL_BLOCKS, 256, 0, stream>>>(
        A, hs1, part1,
        ta, words, emb_w, Wc + 529, bc + 1, tb, nullptr, nullptr, nullptr);

    // P2: xs2 = xs1 + part1 ; hs2 = relu(W2 xs2 + b2)
    gnn_prep<<<N_ATOMS / 128, 128, 0, stream>>>(
        xs1, part1, Wg + 200, bg + 20, xs2, hs2);

    // F2: conv-L2 (+ fused hp) || gnn-L2
    fused_layer<<<TOTAL_BLOCKS, 256, 0, stream>>>(
        A, hs2, part2,
        tb, words, emb_w, Wc + 1058, bc + 2, nullptr, Wa, ba, hpb);

    // comp partials once (tiny)
    comp_reduce<<<16, 256, 0, stream>>>(xs2, part2, comp_part);

    // ATTN over full machine (+ final MLP in last-arriving block)
    attn_final<<<ATT_BLOCKS, 256, 0, stream>>>(
        comp_part, hpb, Wa, ba, Wo, bo, Wi, bi, att_part, ticket, out);
}